// Round 13
// baseline (487.951 us; speedup 1.0000x reference)
//
#include <hip/hip_runtime.h>
#include <hip/hip_bf16.h>
#include <math.h>

#define D 2048
#define H_ 16
#define HD 128
#define L_ 2
#define V_ 32000
#define BS_ 16
#define B_ 16
#define MAXCTX 1024
#define NBLK 64
#define FF 8192
#define SPLITS 8
#define CHUNK 128

__device__ __forceinline__ unsigned short f2bf(float f) {
  unsigned u = __float_as_uint(f);
  unsigned r = (u + 0x7FFFu + ((u >> 16) & 1u)) >> 16;   // RTN-even
  return (unsigned short)r;
}

// ---------------- layernorm (no affine), float4, optional embed-gather + zeroing ----------------
// If Tbf != nullptr, T is written as packed bf16 (for the logits kernel) instead of f32.
__global__ void ln_kernel(const float* __restrict__ X,
                          const int* __restrict__ ids,
                          const float* __restrict__ wte,
                          float* __restrict__ Xout,
                          float* __restrict__ T,
                          unsigned short* __restrict__ Tbf,
                          float* __restrict__ Z, int zfloats) {
  if (blockIdx.x >= B_) {
    int nb = gridDim.x - B_;
    int idx = (blockIdx.x - B_) * 256 + threadIdx.x;
    int n4 = zfloats >> 2;
    float4* z4 = (float4*)Z;
    for (int i = idx; i < n4; i += nb * 256) z4[i] = make_float4(0.f, 0.f, 0.f, 0.f);
    return;
  }
  __shared__ float red[8];
  int b = blockIdx.x, tid = threadIdx.x;
  int wid = tid >> 6, lane = tid & 63;
  const float4* src = (const float4*)(ids ? (wte + (size_t)ids[b] * D) : (X + (size_t)b * D));
  float4 v0 = src[tid], v1 = src[tid + 256];
  if (ids) {
    float4* xo = (float4*)(Xout + (size_t)b * D);
    xo[tid] = v0; xo[tid + 256] = v1;
  }
  float s = v0.x + v0.y + v0.z + v0.w + v1.x + v1.y + v1.z + v1.w;
#pragma unroll
  for (int m = 32; m; m >>= 1) s += __shfl_xor(s, m);
  if (lane == 0) red[wid] = s;
  __syncthreads();
  float mu = (red[0] + red[1] + red[2] + red[3]) * (1.f / D);
  float d0 = v0.x - mu, d1 = v0.y - mu, d2 = v0.z - mu, d3 = v0.w - mu;
  float d4 = v1.x - mu, d5 = v1.y - mu, d6 = v1.z - mu, d7 = v1.w - mu;
  float vs = d0*d0 + d1*d1 + d2*d2 + d3*d3 + d4*d4 + d5*d5 + d6*d6 + d7*d7;
#pragma unroll
  for (int m = 32; m; m >>= 1) vs += __shfl_xor(vs, m);
  if (lane == 0) red[4 + wid] = vs;
  __syncthreads();
  float var = (red[4] + red[5] + red[6] + red[7]) * (1.f / D);
  float r = 1.f / sqrtf(var + 1e-5f);
  if (Tbf) {
    ushort4* tb = (ushort4*)(Tbf + (size_t)b * D);
    ushort4 o0, o1;
    o0.x = f2bf(d0 * r); o0.y = f2bf(d1 * r); o0.z = f2bf(d2 * r); o0.w = f2bf(d3 * r);
    o1.x = f2bf(d4 * r); o1.y = f2bf(d5 * r); o1.z = f2bf(d6 * r); o1.w = f2bf(d7 * r);
    tb[tid] = o0; tb[tid + 256] = o1;
  } else {
    float4* t4 = (float4*)(T + (size_t)b * D);
    t4[tid]       = make_float4(d0 * r, d1 * r, d2 * r, d3 * r);
    t4[tid + 256] = make_float4(d4 * r, d5 * r, d6 * r, d7 * r);
  }
}

// ---- 256-deep-k gemm tail (R10-proven): p-th 64-k slice per wave, LDS 4-way combine,
// ---- ONE atomicAdd per output per block. k=256 beats k=128/k=32 splits (R8/R12).
#define GEMM256_TAIL(TL, COMB, WP, NSTRIDE, OPTR, JBASE, C, P, TID)                \
  {                                                                                \
    float acc[16];                                                                 \
    _Pragma("unroll") for (int b = 0; b < 16; b++) acc[b] = 0.f;                   \
    const float* wp_ = (WP);                                                       \
    _Pragma("unroll 4") for (int k = 0; k < 64; k++) {                             \
      float w = wp_[(size_t)k * (NSTRIDE)];                                        \
      const float4* tr = (const float4*)(&TL[(P) * 64 + k][0]);                    \
      float4 t0 = tr[0], t1 = tr[1], t2 = tr[2], t3 = tr[3];                       \
      acc[0]  += t0.x * w; acc[1]  += t0.y * w; acc[2]  += t0.z * w; acc[3]  += t0.w * w; \
      acc[4]  += t1.x * w; acc[5]  += t1.y * w; acc[6]  += t1.z * w; acc[7]  += t1.w * w; \
      acc[8]  += t2.x * w; acc[9]  += t2.y * w; acc[10] += t2.z * w; acc[11] += t2.w * w; \
      acc[12] += t3.x * w; acc[13] += t3.y * w; acc[14] += t3.z * w; acc[15] += t3.w * w; \
    }                                                                              \
    _Pragma("unroll") for (int b = 0; b < 16; b++) COMB[P][(C) * 17 + b] = acc[b]; \
    __syncthreads();                                                               \
    _Pragma("unroll") for (int r = 0; r < 4; r++) {                                \
      int o = r * 256 + (TID);                                                     \
      int bb = o >> 6, cc = o & 63;                                                \
      float v = COMB[0][cc*17+bb] + COMB[1][cc*17+bb] + COMB[2][cc*17+bb] + COMB[3][cc*17+bb]; \
      atomicAdd(&(OPTR)[(size_t)bb * (NSTRIDE) + (JBASE) + cc], v);                \
    }                                                                              \
  }

// ---------------- generic gemm (k_per_block=256, j_tile=64): O(16,N) += T(16,K) @ W(K,N) ----------------
__global__ void gemm256_kernel(const float* __restrict__ T,
                               const float* __restrict__ W,
                               float* __restrict__ O,
                               int K, int N) {
  __shared__ __align__(16) float tl[256][20];
  __shared__ float comb[4][64 * 17];
  int tid = threadIdx.x;
  int c = tid & 63, p = tid >> 6;
  int jbase = blockIdx.x * 64;
  int k0 = blockIdx.y * 256;
#pragma unroll
  for (int r = 0; r < 16; r++) {
    int ii = tid + r * 256;
    int b = ii >> 8, k = ii & 255;
    tl[k][b] = T[(size_t)b * K + k0 + k];
  }
  __syncthreads();
  GEMM256_TAIL(tl, comb, W + (size_t)(k0 + p * 64) * N + jbase + c, N, O, jbase, c, p, tid)
}

// ---------------- fused Q+KV gemm (k=256): blocks x<32 -> q, x>=32 -> kv ----------------
__global__ void qkv_gemm_kernel(const float* __restrict__ T,
                                const float* __restrict__ Wq,
                                const float* __restrict__ Wkv,
                                float* __restrict__ Qo,
                                float* __restrict__ KVo) {
  __shared__ __align__(16) float tl[256][20];
  __shared__ float comb[4][64 * 17];
  int tid = threadIdx.x;
  int c = tid & 63, p = tid >> 6;
  int k0 = blockIdx.y * 256;
#pragma unroll
  for (int r = 0; r < 16; r++) {
    int ii = tid + r * 256;
    int b = ii >> 8, k = ii & 255;
    tl[k][b] = T[(size_t)b * D + k0 + k];
  }
  __syncthreads();
  if (blockIdx.x < 32) {
    int jbase = blockIdx.x * 64;
    GEMM256_TAIL(tl, comb, Wq + (size_t)(k0 + p * 64) * D + jbase + c, D, Qo, jbase, c, p, tid)
  } else {
    int jbase = (blockIdx.x - 32) * 64;
    GEMM256_TAIL(tl, comb, Wkv + (size_t)(k0 + p * 64) * 256 + jbase + c, 256, KVo, jbase, c, p, tid)
  }
}

// ---------------- attention split (flash-decoding): block per (b,h,split) ----------------
__global__ void attn_split_kernel(const float* __restrict__ Q,    // (16, 2048)
                                  const float* __restrict__ KVn,  // (16, 256)
                                  const float* __restrict__ KC,
                                  const float* __restrict__ VC,
                                  const int* __restrict__ BT,     // (16, 64)
                                  const int* __restrict__ CL,
                                  float* __restrict__ Pout,       // (256, 8, 128)
                                  float* __restrict__ Pms) {      // (256, 8, 2)
  int bh = blockIdx.x, sp = blockIdx.y;
  int b = bh >> 4, h = bh & 15;
  int ctx = CL[b];
  int s0 = sp * CHUNK;
  if (s0 >= ctx) return;
  int s1 = min(s0 + CHUNK, ctx);
  int n = s1 - s0;
  int last = ctx - 1;
  int tid = threadIdx.x, wid = tid >> 6, lane = tid & 63;
  int half = lane >> 5, l32 = lane & 31;
  __shared__ float sc[CHUNK];
  __shared__ int btl[8];
  __shared__ float4 red[4][64];
  __shared__ float stat[8];
  if (tid < 8) btl[tid] = BT[b * NBLK + sp * 8 + tid];
  __syncthreads();
  float slope = exp2f(-0.5f * (float)(h + 1));
  const float scl = 0.08838834764831845f;   // 1/sqrt(128)
  float4 q4 = ((const float4*)(Q + (size_t)b * D + h * HD))[l32];

  // phase 1: scores — half-wave per position
  for (int base = s0 + wid * 2; base < s1; base += 8) {
    int ps = base + half;
    if (ps < s1) {
      const float* kp = (ps == last) ? KVn + b * 256
                      : KC + ((size_t)btl[(ps - s0) >> 4] * BS_ + (ps & 15)) * (H_ * HD) + h * HD;
      float4 k4 = ((const float4*)kp)[l32];
      float p = q4.x * k4.x + q4.y * k4.y + q4.z * k4.z + q4.w * k4.w;
#pragma unroll
      for (int m = 16; m; m >>= 1) p += __shfl_xor(p, m);
      if (l32 == 0) sc[ps - s0] = p * scl + slope * (float)(ps - last);
    }
  }
  __syncthreads();

  // phase 2: local softmax stats (unnormalized)
  float mx = -1e30f;
  for (int i = tid; i < n; i += 256) mx = fmaxf(mx, sc[i]);
#pragma unroll
  for (int m = 32; m; m >>= 1) mx = fmaxf(mx, __shfl_xor(mx, m));
  if (lane == 0) stat[wid] = mx;
  __syncthreads();
  mx = fmaxf(fmaxf(stat[0], stat[1]), fmaxf(stat[2], stat[3]));
  float sum = 0.f;
  for (int i = tid; i < n; i += 256) { float e = expf(sc[i] - mx); sc[i] = e; sum += e; }
#pragma unroll
  for (int m = 32; m; m >>= 1) sum += __shfl_xor(sum, m);
  if (lane == 0) stat[4 + wid] = sum;
  __syncthreads();

  // phase 3: PV partial (unnormalized) — half-wave per position, float4
  float4 a4 = make_float4(0.f, 0.f, 0.f, 0.f);
  for (int base = s0 + wid * 2; base < s1; base += 8) {
    int ps = base + half;
    if (ps < s1) {
      const float* vp = (ps == last) ? KVn + b * 256 + HD
                      : VC + ((size_t)btl[(ps - s0) >> 4] * BS_ + (ps & 15)) * (H_ * HD) + h * HD;
      float4 v4 = ((const float4*)vp)[l32];
      float p = sc[ps - s0];
      a4.x += p * v4.x; a4.y += p * v4.y; a4.z += p * v4.z; a4.w += p * v4.w;
    }
  }
  red[wid][lane] = a4;
  __syncthreads();
  if (tid < 32) {
    float4 o = make_float4(0.f, 0.f, 0.f, 0.f);
#pragma unroll
    for (int w = 0; w < 4; w++) {
      float4 r0 = red[w][tid], r1 = red[w][tid + 32];
      o.x += r0.x + r1.x; o.y += r0.y + r1.y;
      o.z += r0.z + r1.z; o.w += r0.w + r1.w;
    }
    ((float4*)(Pout + ((size_t)(bh * SPLITS + sp) << 7)))[tid] = o;
  }
  if (tid == 0) {
    Pms[(bh * SPLITS + sp) * 2 + 0] = mx;
    Pms[(bh * SPLITS + sp) * 2 + 1] = stat[4] + stat[5] + stat[6] + stat[7];
  }
}

// ---------------- Wo gemm (k=256) with fused attention-combine staging ----------------
__global__ void wo_gemm_kernel(const float* __restrict__ Pout,
                               const float* __restrict__ Pms,
                               const int* __restrict__ CL,
                               const float* __restrict__ W,
                               float* __restrict__ X) {
  __shared__ __align__(16) float tl[256][20];
  __shared__ float comb[4][64 * 17];
  __shared__ float wgt[16][2][8];
  __shared__ int nspl[16];
  int tid = threadIdx.x;
  int c = tid & 63, p = tid >> 6;
  int jbase = blockIdx.x * 64;
  int k0 = blockIdx.y * 256;
  int h0 = k0 >> 7;
  if (tid < 32) {
    int b = tid & 15, hh = tid >> 4;
    int h = h0 + hh;
    int ctx = CL[b];
    int nsp = (ctx + CHUNK - 1) >> 7;
    if (hh == 0) nspl[b] = nsp;
    int bh = b * 16 + h;
    float M = -1e30f;
#pragma unroll
    for (int i = 0; i < 8; i++) {
      float mi = (i < nsp) ? Pms[(bh * SPLITS + i) * 2] : -1e30f;
      M = fmaxf(M, mi);
    }
    float tot = 0.f, e[8];
#pragma unroll
    for (int i = 0; i < 8; i++) {
      float mi = (i < nsp) ? Pms[(bh * SPLITS + i) * 2] : -1e30f;
      float si = (i < nsp) ? Pms[(bh * SPLITS + i) * 2 + 1] : 0.f;
      e[i] = (i < nsp) ? expf(mi - M) : 0.f;
      tot += e[i] * si;
    }
    float inv = 1.f / tot;
#pragma unroll
    for (int i = 0; i < 8; i++) wgt[b][hh][i] = e[i] * inv;
  }
  __syncthreads();
#pragma unroll
  for (int r = 0; r < 16; r++) {
    int ii = tid + r * 256;
    int b = ii >> 8, k = ii & 255;
    int hh = k >> 7, dd = k & 127;
    int bh = b * 16 + h0 + hh;
    int ns = nspl[b];
    float v = 0.f;
    for (int i = 0; i < ns; i++)
      v += wgt[b][hh][i] * Pout[((size_t)(bh * SPLITS + i) << 7) + dd];
    tl[k][b] = v;
  }
  __syncthreads();
  GEMM256_TAIL(tl, comb, W + (size_t)(k0 + p * 64) * D + jbase + c, D, X, jbase, c, p, tid)
}

// ---------------- Wff2 gemm (k=256) with fused swiglu staging ----------------
__global__ void ff2_gemm_kernel(const float* __restrict__ Hb,
                                const float* __restrict__ W,
                                float* __restrict__ X) {
  __shared__ __align__(16) float tl[256][20];
  __shared__ float comb[4][64 * 17];
  int tid = threadIdx.x;
  int c = tid & 63, p = tid >> 6;
  int jbase = blockIdx.x * 64;
  int k0 = blockIdx.y * 256;
#pragma unroll
  for (int r = 0; r < 16; r++) {
    int ii = tid + r * 256;
    int b = ii >> 8, k = ii & 255;
    float a = Hb[(size_t)b * FF + k0 + k];
    float g = Hb[(size_t)b * FF + 4096 + k0 + k];
    tl[k][b] = a * (g / (1.f + expf(-g)));
  }
  __syncthreads();
  GEMM256_TAIL(tl, comb, W + (size_t)(k0 + p * 64) * D + jbase + c, D, X, jbase, c, p, tid)
}

// ---------------- logits: out(16,V) = Tbf(16,2048 bf16) @ wte(V,2048)^T ----------------
// R10-PROVEN STRUCTURE — only the T load type changed (f32 -> bf16, halves the
// L2-bound T stream: 41B/cy/CU -> 20, freeing the L2 pipe for the wte HBM stream).
// Spill lore: (a) VGPR cap <=128 -> 64-tier + 600-770MB scratch writes (R4/R6/R8);
// (b) acc[32]/8-rows: 1.8x VMEM per wte byte, +36us (R9);
// (c) LDS-staged T with acc[64] live across barriers -> 128-tier spill, +160us (R11).
__global__ __launch_bounds__(256, 2)
void logits_kernel(const unsigned short* __restrict__ Tb,
                   const float* __restrict__ wte,
                   float* __restrict__ O) {
  int tid = threadIdx.x;
  int wid = tid >> 6, lane = tid & 63;
  int vbase = blockIdx.x * 16 + wid * 4;
  const ushort4* T4 = (const ushort4*)Tb;         // 16 rows x 512 ushort4 (bf16)
  const float4* W4 = (const float4*)(wte + (size_t)vbase * D);
  float acc[64];                                   // flat index = b*4 + vi
#pragma unroll
  for (int j = 0; j < 64; j++) acc[j] = 0.f;

#pragma unroll 2
  for (int it = 0; it < 8; it++) {
    int idx = it * 64 + lane;                      // vec4 index within row
    float4 w0 = W4[idx];
    float4 w1 = W4[512 + idx];
    float4 w2 = W4[1024 + idx];
    float4 w3 = W4[1536 + idx];
#pragma unroll
    for (int b = 0; b < 16; b++) {
      ushort4 tu = T4[b * 512 + idx];
      float4 t4 = make_float4(__uint_as_float((unsigned)tu.x << 16),
                              __uint_as_float((unsigned)tu.y << 16),
                              __uint_as_float((unsigned)tu.z << 16),
                              __uint_as_float((unsigned)tu.w << 16));
      acc[b * 4 + 0] += t4.x * w0.x + t4.y * w0.y + t4.z * w0.z + t4.w * w0.w;
      acc[b * 4 + 1] += t4.x * w1.x + t4.y * w1.y + t4.z * w1.z + t4.w * w1.w;
      acc[b * 4 + 2] += t4.x * w2.x + t4.y * w2.y + t4.z * w2.z + t4.w * w2.w;
      acc[b * 4 + 3] += t4.x * w3.x + t4.y * w3.y + t4.z * w3.z + t4.w * w3.w;
    }
  }

  // multi-value butterfly reduce: 64 lane-sums in 63 shfls; lane l ends with flat index l.
#pragma unroll
  for (int st = 0; st < 6; st++) {
    const int m = 1 << st;
    const int nn = 64 >> (st + 1);
    const bool hi = (lane & m) != 0;
#pragma unroll
    for (int i = 0; i < nn; i++) {
      float a = acc[2 * i], b = acc[2 * i + 1];
      float send = hi ? a : b;
      float keep = hi ? b : a;
      acc[i] = keep + __shfl_xor(send, m);
    }
  }
  O[(size_t)(lane >> 2) * V_ + vbase + (lane & 3)] = acc[0];
}

extern "C" void kernel_launch(void* const* d_in, const int* in_sizes, int n_in,
                              void* d_out, int out_size, void* d_ws, size_t ws_size,
                              hipStream_t stream) {
  const int* ids   = (const int*)d_in[0];
  const int* bt    = (const int*)d_in[2];
  const int* cl    = (const int*)d_in[3];
  const float* wte = (const float*)d_in[5];
  const float* Wq  = (const float*)d_in[6];
  const float* Wkv = (const float*)d_in[7];
  const float* Wo  = (const float*)d_in[8];
  const float* Wff1= (const float*)d_in[9];
  const float* Wff2= (const float*)d_in[10];
  const float* KC  = (const float*)d_in[11];
  const float* VC  = (const float*)d_in[12];
  float* out = (float*)d_out;
  float* ws  = (float*)d_ws;

  // workspace layout (floats)
  float* x    = ws;             // 16*2048
  float* t    = ws + 32768;     // 16*2048
  float* q    = ws + 65536;     // 16*2048
  float* kv   = ws + 98304;     // 16*256   (contiguous after q -> zeroed together)
  float* hb   = ws + 135168;    // 16*8192
  float* pout = ws + 331776;    // 256*8*128
  float* pms  = ws + 593920;    // 256*8*2
  unsigned short* tb = (unsigned short*)(ws + 598016);  // 16*2048 bf16

  for (int l = 0; l < L_; l++) {
    // t = ln(x) (layer 0: x = wte[ids] gathered inline); surplus blocks zero q+kv
    ln_kernel<<<16 + 64, 256, 0, stream>>>(x, l == 0 ? ids : nullptr, wte, x, t, nullptr, q, 32768 + 4096);
    qkv_gemm_kernel<<<dim3(36, 8), 256, 0, stream>>>(t, Wq + (size_t)l * 4194304,
                                                     Wkv + (size_t)l * 524288, q, kv);
    attn_split_kernel<<<dim3(256, SPLITS), 256, 0, stream>>>(q, kv,
                                         KC + (size_t)l * 33554432,
                                         VC + (size_t)l * 33554432,
                                         bt, cl, pout, pms);
    wo_gemm_kernel<<<dim3(32, 8), 256, 0, stream>>>(pout, pms, cl, Wo + (size_t)l * 4194304, x);
    // t = ln(x); surplus blocks zero hb
    ln_kernel<<<16 + 128, 256, 0, stream>>>(x, nullptr, wte, x, t, nullptr, hb, 131072);
    gemm256_kernel<<<dim3(128, 8), 256, 0, stream>>>(t, Wff1 + (size_t)l * 16777216, hb, 2048, 8192);
    ff2_gemm_kernel<<<dim3(32, 16), 256, 0, stream>>>(hb, Wff2 + (size_t)l * 8388608, x);
  }
  // final LN writes bf16 T for the logits kernel
  ln_kernel<<<16, 256, 0, stream>>>(x, nullptr, wte, x, t, tb, (float*)nullptr, 0);
  logits_kernel<<<2000, 256, 0, stream>>>(tb, wte, out);
}

// Round 17
// 325.970 us; speedup vs baseline: 1.4969x; 1.4969x over previous
//
#include <hip/hip_runtime.h>
#include <hip/hip_bf16.h>
#include <math.h>

#define D 2048
#define H_ 16
#define HD 128
#define L_ 2
#define V_ 32000
#define BS_ 16
#define B_ 16
#define MAXCTX 1024
#define NBLK 64
#define FF 8192
#define SPLITS 8
#define CHUNK 128

// ---------------- layernorm (no affine), float4, optional embed-gather + zeroing ----------------
__global__ void ln_kernel(const float* __restrict__ X,
                          const int* __restrict__ ids,
                          const float* __restrict__ wte,
                          float* __restrict__ Xout,
                          float* __restrict__ T,
                          float* __restrict__ Z, int zfloats) {
  if (blockIdx.x >= B_) {
    int nb = gridDim.x - B_;
    int idx = (blockIdx.x - B_) * 256 + threadIdx.x;
    int n4 = zfloats >> 2;
    float4* z4 = (float4*)Z;
    for (int i = idx; i < n4; i += nb * 256) z4[i] = make_float4(0.f, 0.f, 0.f, 0.f);
    return;
  }
  __shared__ float red[8];
  int b = blockIdx.x, tid = threadIdx.x;
  int wid = tid >> 6, lane = tid & 63;
  const float4* src = (const float4*)(ids ? (wte + (size_t)ids[b] * D) : (X + (size_t)b * D));
  float4 v0 = src[tid], v1 = src[tid + 256];
  if (ids) {
    float4* xo = (float4*)(Xout + (size_t)b * D);
    xo[tid] = v0; xo[tid + 256] = v1;
  }
  float s = v0.x + v0.y + v0.z + v0.w + v1.x + v1.y + v1.z + v1.w;
#pragma unroll
  for (int m = 32; m; m >>= 1) s += __shfl_xor(s, m);
  if (lane == 0) red[wid] = s;
  __syncthreads();
  float mu = (red[0] + red[1] + red[2] + red[3]) * (1.f / D);
  float d0 = v0.x - mu, d1 = v0.y - mu, d2 = v0.z - mu, d3 = v0.w - mu;
  float d4 = v1.x - mu, d5 = v1.y - mu, d6 = v1.z - mu, d7 = v1.w - mu;
  float vs = d0*d0 + d1*d1 + d2*d2 + d3*d3 + d4*d4 + d5*d5 + d6*d6 + d7*d7;
#pragma unroll
  for (int m = 32; m; m >>= 1) vs += __shfl_xor(vs, m);
  if (lane == 0) red[4 + wid] = vs;
  __syncthreads();
  float var = (red[4] + red[5] + red[6] + red[7]) * (1.f / D);
  float r = 1.f / sqrtf(var + 1e-5f);
  float4* t4 = (float4*)(T + (size_t)b * D);
  t4[tid]       = make_float4(d0 * r, d1 * r, d2 * r, d3 * r);
  t4[tid + 256] = make_float4(d4 * r, d5 * r, d6 * r, d7 * r);
}

// ---- 256-deep-k gemm tail (R10-proven): p-th 64-k slice per wave, LDS 4-way combine,
// ---- ONE atomicAdd per output per block. unroll 4 (R10-exact; unroll-8 untested —
// ---- three infra failures in a row, reverted to de-risk).
#define GEMM256_TAIL(TL, COMB, WP, NSTRIDE, OPTR, JBASE, C, P, TID)                \
  {                                                                                \
    float acc[16];                                                                 \
    _Pragma("unroll") for (int b = 0; b < 16; b++) acc[b] = 0.f;                   \
    const float* wp_ = (WP);                                                       \
    _Pragma("unroll 4") for (int k = 0; k < 64; k++) {                             \
      float w = wp_[(size_t)k * (NSTRIDE)];                                        \
      const float4* tr = (const float4*)(&TL[(P) * 64 + k][0]);                    \
      float4 t0 = tr[0], t1 = tr[1], t2 = tr[2], t3 = tr[3];                       \
      acc[0]  += t0.x * w; acc[1]  += t0.y * w; acc[2]  += t0.z * w; acc[3]  += t0.w * w; \
      acc[4]  += t1.x * w; acc[5]  += t1.y * w; acc[6]  += t1.z * w; acc[7]  += t1.w * w; \
      acc[8]  += t2.x * w; acc[9]  += t2.y * w; acc[10] += t2.z * w; acc[11] += t2.w * w; \
      acc[12] += t3.x * w; acc[13] += t3.y * w; acc[14] += t3.z * w; acc[15] += t3.w * w; \
    }                                                                              \
    _Pragma("unroll") for (int b = 0; b < 16; b++) COMB[P][(C) * 17 + b] = acc[b]; \
    __syncthreads();                                                               \
    _Pragma("unroll") for (int r = 0; r < 4; r++) {                                \
      int o = r * 256 + (TID);                                                     \
      int bb = o >> 6, cc = o & 63;                                                \
      float v = COMB[0][cc*17+bb] + COMB[1][cc*17+bb] + COMB[2][cc*17+bb] + COMB[3][cc*17+bb]; \
      atomicAdd(&(OPTR)[(size_t)bb * (NSTRIDE) + (JBASE) + cc], v);                \
    }                                                                              \
  }

// ---------------- generic gemm (k_per_block=256, j_tile=64): O(16,N) += T(16,K) @ W(K,N) ----------------
__global__ void gemm256_kernel(const float* __restrict__ T,
                               const float* __restrict__ W,
                               float* __restrict__ O,
                               int K, int N) {
  __shared__ __align__(16) float tl[256][20];
  __shared__ float comb[4][64 * 17];
  int tid = threadIdx.x;
  int c = tid & 63, p = tid >> 6;
  int jbase = blockIdx.x * 64;
  int k0 = blockIdx.y * 256;
#pragma unroll
  for (int r = 0; r < 16; r++) {
    int ii = tid + r * 256;
    int b = ii >> 8, k = ii & 255;
    tl[k][b] = T[(size_t)b * K + k0 + k];
  }
  __syncthreads();
  GEMM256_TAIL(tl, comb, W + (size_t)(k0 + p * 64) * N + jbase + c, N, O, jbase, c, p, tid)
}

// ---------------- fused Q+KV gemm (k=256): blocks x<32 -> q, x>=32 -> kv ----------------
__global__ void qkv_gemm_kernel(const float* __restrict__ T,
                                const float* __restrict__ Wq,
                                const float* __restrict__ Wkv,
                                float* __restrict__ Qo,
                                float* __restrict__ KVo) {
  __shared__ __align__(16) float tl[256][20];
  __shared__ float comb[4][64 * 17];
  int tid = threadIdx.x;
  int c = tid & 63, p = tid >> 6;
  int k0 = blockIdx.y * 256;
#pragma unroll
  for (int r = 0; r < 16; r++) {
    int ii = tid + r * 256;
    int b = ii >> 8, k = ii & 255;
    tl[k][b] = T[(size_t)b * D + k0 + k];
  }
  __syncthreads();
  if (blockIdx.x < 32) {
    int jbase = blockIdx.x * 64;
    GEMM256_TAIL(tl, comb, Wq + (size_t)(k0 + p * 64) * D + jbase + c, D, Qo, jbase, c, p, tid)
  } else {
    int jbase = (blockIdx.x - 32) * 64;
    GEMM256_TAIL(tl, comb, Wkv + (size_t)(k0 + p * 64) * 256 + jbase + c, 256, KVo, jbase, c, p, tid)
  }
}

// ---------------- attention split (flash-decoding): block per (b,h,split) ----------------
__global__ void attn_split_kernel(const float* __restrict__ Q,    // (16, 2048)
                                  const float* __restrict__ KVn,  // (16, 256)
                                  const float* __restrict__ KC,
                                  const float* __restrict__ VC,
                                  const int* __restrict__ BT,     // (16, 64)
                                  const int* __restrict__ CL,
                                  float* __restrict__ Pout,       // (256, 8, 128)
                                  float* __restrict__ Pms) {      // (256, 8, 2)
  int bh = blockIdx.x, sp = blockIdx.y;
  int b = bh >> 4, h = bh & 15;
  int ctx = CL[b];
  int s0 = sp * CHUNK;
  if (s0 >= ctx) return;
  int s1 = min(s0 + CHUNK, ctx);
  int n = s1 - s0;
  int last = ctx - 1;
  int tid = threadIdx.x, wid = tid >> 6, lane = tid & 63;
  int half = lane >> 5, l32 = lane & 31;
  __shared__ float sc[CHUNK];
  __shared__ int btl[8];
  __shared__ float4 red[4][64];
  __shared__ float stat[8];
  if (tid < 8) btl[tid] = BT[b * NBLK + sp * 8 + tid];
  __syncthreads();
  float slope = exp2f(-0.5f * (float)(h + 1));
  const float scl = 0.08838834764831845f;   // 1/sqrt(128)
  float4 q4 = ((const float4*)(Q + (size_t)b * D + h * HD))[l32];

  // phase 1: scores — half-wave per position
  for (int base = s0 + wid * 2; base < s1; base += 8) {
    int ps = base + half;
    if (ps < s1) {
      const float* kp = (ps == last) ? KVn + b * 256
                      : KC + ((size_t)btl[(ps - s0) >> 4] * BS_ + (ps & 15)) * (H_ * HD) + h * HD;
      float4 k4 = ((const float4*)kp)[l32];
      float p = q4.x * k4.x + q4.y * k4.y + q4.z * k4.z + q4.w * k4.w;
#pragma unroll
      for (int m = 16; m; m >>= 1) p += __shfl_xor(p, m);
      if (l32 == 0) sc[ps - s0] = p * scl + slope * (float)(ps - last);
    }
  }
  __syncthreads();

  // phase 2: local softmax stats (unnormalized)
  float mx = -1e30f;
  for (int i = tid; i < n; i += 256) mx = fmaxf(mx, sc[i]);
#pragma unroll
  for (int m = 32; m; m >>= 1) mx = fmaxf(mx, __shfl_xor(mx, m));
  if (lane == 0) stat[wid] = mx;
  __syncthreads();
  mx = fmaxf(fmaxf(stat[0], stat[1]), fmaxf(stat[2], stat[3]));
  float sum = 0.f;
  for (int i = tid; i < n; i += 256) { float e = expf(sc[i] - mx); sc[i] = e; sum += e; }
#pragma unroll
  for (int m = 32; m; m >>= 1) sum += __shfl_xor(sum, m);
  if (lane == 0) stat[4 + wid] = sum;
  __syncthreads();

  // phase 3: PV partial (unnormalized) — half-wave per position, float4
  float4 a4 = make_float4(0.f, 0.f, 0.f, 0.f);
  for (int base = s0 + wid * 2; base < s1; base += 8) {
    int ps = base + half;
    if (ps < s1) {
      const float* vp = (ps == last) ? KVn + b * 256 + HD
                      : VC + ((size_t)btl[(ps - s0) >> 4] * BS_ + (ps & 15)) * (H_ * HD) + h * HD;
      float4 v4 = ((const float4*)vp)[l32];
      float p = sc[ps - s0];
      a4.x += p * v4.x; a4.y += p * v4.y; a4.z += p * v4.z; a4.w += p * v4.w;
    }
  }
  red[wid][lane] = a4;
  __syncthreads();
  if (tid < 32) {
    float4 o = make_float4(0.f, 0.f, 0.f, 0.f);
#pragma unroll
    for (int w = 0; w < 4; w++) {
      float4 r0 = red[w][tid], r1 = red[w][tid + 32];
      o.x += r0.x + r1.x; o.y += r0.y + r1.y;
      o.z += r0.z + r1.z; o.w += r0.w + r1.w;
    }
    ((float4*)(Pout + ((size_t)(bh * SPLITS + sp) << 7)))[tid] = o;
  }
  if (tid == 0) {
    Pms[(bh * SPLITS + sp) * 2 + 0] = mx;
    Pms[(bh * SPLITS + sp) * 2 + 1] = stat[4] + stat[5] + stat[6] + stat[7];
  }
}

// ---------------- Wo gemm (k=256) with fused attention-combine staging ----------------
__global__ void wo_gemm_kernel(const float* __restrict__ Pout,
                               const float* __restrict__ Pms,
                               const int* __restrict__ CL,
                               const float* __restrict__ W,
                               float* __restrict__ X) {
  __shared__ __align__(16) float tl[256][20];
  __shared__ float comb[4][64 * 17];
  __shared__ float wgt[16][2][8];
  __shared__ int nspl[16];
  int tid = threadIdx.x;
  int c = tid & 63, p = tid >> 6;
  int jbase = blockIdx.x * 64;
  int k0 = blockIdx.y * 256;
  int h0 = k0 >> 7;
  if (tid < 32) {
    int b = tid & 15, hh = tid >> 4;
    int h = h0 + hh;
    int ctx = CL[b];
    int nsp = (ctx + CHUNK - 1) >> 7;
    if (hh == 0) nspl[b] = nsp;
    int bh = b * 16 + h;
    float M = -1e30f;
#pragma unroll
    for (int i = 0; i < 8; i++) {
      float mi = (i < nsp) ? Pms[(bh * SPLITS + i) * 2] : -1e30f;
      M = fmaxf(M, mi);
    }
    float tot = 0.f, e[8];
#pragma unroll
    for (int i = 0; i < 8; i++) {
      float mi = (i < nsp) ? Pms[(bh * SPLITS + i) * 2] : -1e30f;
      float si = (i < nsp) ? Pms[(bh * SPLITS + i) * 2 + 1] : 0.f;
      e[i] = (i < nsp) ? expf(mi - M) : 0.f;
      tot += e[i] * si;
    }
    float inv = 1.f / tot;
#pragma unroll
    for (int i = 0; i < 8; i++) wgt[b][hh][i] = e[i] * inv;
  }
  __syncthreads();
#pragma unroll
  for (int r = 0; r < 16; r++) {
    int ii = tid + r * 256;
    int b = ii >> 8, k = ii & 255;
    int hh = k >> 7, dd = k & 127;
    int bh = b * 16 + h0 + hh;
    int ns = nspl[b];
    float v = 0.f;
    for (int i = 0; i < ns; i++)
      v += wgt[b][hh][i] * Pout[((size_t)(bh * SPLITS + i) << 7) + dd];
    tl[k][b] = v;
  }
  __syncthreads();
  GEMM256_TAIL(tl, comb, W + (size_t)(k0 + p * 64) * D + jbase + c, D, X, jbase, c, p, tid)
}

// ---------------- Wff2 gemm (k=256) with fused swiglu staging ----------------
__global__ void ff2_gemm_kernel(const float* __restrict__ Hb,
                                const float* __restrict__ W,
                                float* __restrict__ X) {
  __shared__ __align__(16) float tl[256][20];
  __shared__ float comb[4][64 * 17];
  int tid = threadIdx.x;
  int c = tid & 63, p = tid >> 6;
  int jbase = blockIdx.x * 64;
  int k0 = blockIdx.y * 256;
#pragma unroll
  for (int r = 0; r < 16; r++) {
    int ii = tid + r * 256;
    int b = ii >> 8, k = ii & 255;
    float a = Hb[(size_t)b * FF + k0 + k];
    float g = Hb[(size_t)b * FF + 4096 + k0 + k];
    tl[k][b] = a * (g / (1.f + expf(-g)));
  }
  __syncthreads();
  GEMM256_TAIL(tl, comb, W + (size_t)(k0 + p * 64) * D + jbase + c, D, X, jbase, c, p, tid)
}

// ---------------- logits: out(16,V) = T(16,2048) @ wte(V,2048)^T ----------------
// R10-PROVEN FINAL FORM — DO NOT MODIFY IN ANY WAY. 16 rows/block, acc[64],
// pure-global f32 loads, launch_bounds(256,2), unroll 2, butterfly reduce.
// Spill lore: (a) VGPR cap <=128 -> 64-tier + 600-770MB scratch writes (R4/R6/R8);
// (b) acc[32]/8-rows: 1.8x VMEM per wte byte, +36us (R9);
// (c) LDS-staged T across barriers -> 128-tier spill, +160us (R11);
// (d) bf16 T loads (ushort4 unpack) -> 128-tier spill, +160us (R13).
__global__ __launch_bounds__(256, 2)
void logits_kernel(const float* __restrict__ T,
                   const float* __restrict__ wte,
                   float* __restrict__ O) {
  int tid = threadIdx.x;
  int wid = tid >> 6, lane = tid & 63;
  int vbase = blockIdx.x * 16 + wid * 4;
  const float4* T4 = (const float4*)T;            // 16 rows x 512 float4
  const float4* W4 = (const float4*)(wte + (size_t)vbase * D);
  float acc[64];                                   // flat index = b*4 + vi
#pragma unroll
  for (int j = 0; j < 64; j++) acc[j] = 0.f;

#pragma unroll 2
  for (int it = 0; it < 8; it++) {
    int idx = it * 64 + lane;                      // float4 index within row
    float4 w0 = W4[idx];
    float4 w1 = W4[512 + idx];
    float4 w2 = W4[1024 + idx];
    float4 w3 = W4[1536 + idx];
#pragma unroll
    for (int b = 0; b < 16; b++) {
      float4 t4 = T4[b * 512 + idx];
      acc[b * 4 + 0] += t4.x * w0.x + t4.y * w0.y + t4.z * w0.z + t4.w * w0.w;
      acc[b * 4 + 1] += t4.x * w1.x + t4.y * w1.y + t4.z * w1.z + t4.w * w1.w;
      acc[b * 4 + 2] += t4.x * w2.x + t4.y * w2.y + t4.z * w2.z + t4.w * w2.w;
      acc[b * 4 + 3] += t4.x * w3.x + t4.y * w3.y + t4.z * w3.z + t4.w * w3.w;
    }
  }

  // multi-value butterfly reduce: 64 lane-sums in 63 shfls; lane l ends with flat index l.
#pragma unroll
  for (int st = 0; st < 6; st++) {
    const int m = 1 << st;
    const int nn = 64 >> (st + 1);
    const bool hi = (lane & m) != 0;
#pragma unroll
    for (int i = 0; i < nn; i++) {
      float a = acc[2 * i], b = acc[2 * i + 1];
      float send = hi ? a : b;
      float keep = hi ? b : a;
      acc[i] = keep + __shfl_xor(send, m);
    }
  }
  O[(size_t)(lane >> 2) * V_ + vbase + (lane & 3)] = acc[0];
}

extern "C" void kernel_launch(void* const* d_in, const int* in_sizes, int n_in,
                              void* d_out, int out_size, void* d_ws, size_t ws_size,
                              hipStream_t stream) {
  const int* ids   = (const int*)d_in[0];
  const int* bt    = (const int*)d_in[2];
  const int* cl    = (const int*)d_in[3];
  const float* wte = (const float*)d_in[5];
  const float* Wq  = (const float*)d_in[6];
  const float* Wkv = (const float*)d_in[7];
  const float* Wo  = (const float*)d_in[8];
  const float* Wff1= (const float*)d_in[9];
  const float* Wff2= (const float*)d_in[10];
  const float* KC  = (const float*)d_in[11];
  const float* VC  = (const float*)d_in[12];
  float* out = (float*)d_out;
  float* ws  = (float*)d_ws;

  // workspace layout (floats)
  float* x    = ws;             // 16*2048
  float* t    = ws + 32768;     // 16*2048
  float* q    = ws + 65536;     // 16*2048
  float* kv   = ws + 98304;     // 16*256   (contiguous after q -> zeroed together)
  float* hb   = ws + 135168;    // 16*8192
  float* pout = ws + 331776;    // 256*8*128
  float* pms  = ws + 593920;    // 256*8*2

  for (int l = 0; l < L_; l++) {
    // t = ln(x) (layer 0: x = wte[ids] gathered inline); surplus blocks zero q+kv
    ln_kernel<<<16 + 64, 256, 0, stream>>>(x, l == 0 ? ids : nullptr, wte, x, t, q, 32768 + 4096);
    qkv_gemm_kernel<<<dim3(36, 8), 256, 0, stream>>>(t, Wq + (size_t)l * 4194304,
                                                     Wkv + (size_t)l * 524288, q, kv);
    attn_split_kernel<<<dim3(256, SPLITS), 256, 0, stream>>>(q, kv,
                                         KC + (size_t)l * 33554432,
                                         VC + (size_t)l * 33554432,
                                         bt, cl, pout, pms);
    wo_gemm_kernel<<<dim3(32, 8), 256, 0, stream>>>(pout, pms, cl, Wo + (size_t)l * 4194304, x);
    // t = ln(x); surplus blocks zero hb
    ln_kernel<<<16 + 128, 256, 0, stream>>>(x, nullptr, wte, x, t, hb, 131072);
    gemm256_kernel<<<dim3(128, 8), 256, 0, stream>>>(t, Wff1 + (size_t)l * 16777216, hb, 2048, 8192);
    ff2_gemm_kernel<<<dim3(32, 16), 256, 0, stream>>>(hb, Wff2 + (size_t)l * 8388608, x);
  }
  ln_kernel<<<16, 256, 0, stream>>>(x, nullptr, wte, x, t, (float*)nullptr, 0);
  logits_kernel<<<2000, 256, 0, stream>>>(t, wte, out);
}

// Round 18
// 307.983 us; speedup vs baseline: 1.5843x; 1.0584x over previous
//
#include <hip/hip_runtime.h>
#include <hip/hip_bf16.h>
#include <math.h>

#define D 2048
#define H_ 16
#define HD 128
#define L_ 2
#define V_ 32000
#define BS_ 16
#define B_ 16
#define MAXCTX 1024
#define NBLK 64
#define FF 8192
#define SPLITS 8
#define CHUNK 128

// ---------------- layernorm (no affine), float4, optional embed-gather + zeroing ----------------
__global__ void ln_kernel(const float* __restrict__ X,
                          const int* __restrict__ ids,
                          const float* __restrict__ wte,
                          float* __restrict__ Xout,
                          float* __restrict__ T,
                          float* __restrict__ Z, int zfloats) {
  if (blockIdx.x >= B_) {
    int nb = gridDim.x - B_;
    int idx = (blockIdx.x - B_) * 256 + threadIdx.x;
    int n4 = zfloats >> 2;
    float4* z4 = (float4*)Z;
    for (int i = idx; i < n4; i += nb * 256) z4[i] = make_float4(0.f, 0.f, 0.f, 0.f);
    return;
  }
  __shared__ float red[8];
  int b = blockIdx.x, tid = threadIdx.x;
  int wid = tid >> 6, lane = tid & 63;
  const float4* src = (const float4*)(ids ? (wte + (size_t)ids[b] * D) : (X + (size_t)b * D));
  float4 v0 = src[tid], v1 = src[tid + 256];
  if (ids) {
    float4* xo = (float4*)(Xout + (size_t)b * D);
    xo[tid] = v0; xo[tid + 256] = v1;
  }
  float s = v0.x + v0.y + v0.z + v0.w + v1.x + v1.y + v1.z + v1.w;
#pragma unroll
  for (int m = 32; m; m >>= 1) s += __shfl_xor(s, m);
  if (lane == 0) red[wid] = s;
  __syncthreads();
  float mu = (red[0] + red[1] + red[2] + red[3]) * (1.f / D);
  float d0 = v0.x - mu, d1 = v0.y - mu, d2 = v0.z - mu, d3 = v0.w - mu;
  float d4 = v1.x - mu, d5 = v1.y - mu, d6 = v1.z - mu, d7 = v1.w - mu;
  float vs = d0*d0 + d1*d1 + d2*d2 + d3*d3 + d4*d4 + d5*d5 + d6*d6 + d7*d7;
#pragma unroll
  for (int m = 32; m; m >>= 1) vs += __shfl_xor(vs, m);
  if (lane == 0) red[4 + wid] = vs;
  __syncthreads();
  float var = (red[4] + red[5] + red[6] + red[7]) * (1.f / D);
  float r = 1.f / sqrtf(var + 1e-5f);
  float4* t4 = (float4*)(T + (size_t)b * D);
  t4[tid]       = make_float4(d0 * r, d1 * r, d2 * r, d3 * r);
  t4[tid + 256] = make_float4(d4 * r, d5 * r, d6 * r, d7 * r);
}

// ---- 256-deep-k gemm tail (R10-proven structure): p-th 64-k slice per wave,
// ---- LDS 4-way combine, ONE atomicAdd per output per block.
// ---- R18 change (single variable vs R17): k-loop unroll 4 -> 8 to double
// ---- in-flight weight loads per wave (gemms measured latency-limited at
// ---- ~4.5KB in-flight/CU vs ~22KB needed for full HBM BW).
#define GEMM256_TAIL(TL, COMB, WP, NSTRIDE, OPTR, JBASE, C, P, TID)                \
  {                                                                                \
    float acc[16];                                                                 \
    _Pragma("unroll") for (int b = 0; b < 16; b++) acc[b] = 0.f;                   \
    const float* wp_ = (WP);                                                       \
    _Pragma("unroll 8") for (int k = 0; k < 64; k++) {                             \
      float w = wp_[(size_t)k * (NSTRIDE)];                                        \
      const float4* tr = (const float4*)(&TL[(P) * 64 + k][0]);                    \
      float4 t0 = tr[0], t1 = tr[1], t2 = tr[2], t3 = tr[3];                       \
      acc[0]  += t0.x * w; acc[1]  += t0.y * w; acc[2]  += t0.z * w; acc[3]  += t0.w * w; \
      acc[4]  += t1.x * w; acc[5]  += t1.y * w; acc[6]  += t1.z * w; acc[7]  += t1.w * w; \
      acc[8]  += t2.x * w; acc[9]  += t2.y * w; acc[10] += t2.z * w; acc[11] += t2.w * w; \
      acc[12] += t3.x * w; acc[13] += t3.y * w; acc[14] += t3.z * w; acc[15] += t3.w * w; \
    }                                                                              \
    _Pragma("unroll") for (int b = 0; b < 16; b++) COMB[P][(C) * 17 + b] = acc[b]; \
    __syncthreads();                                                               \
    _Pragma("unroll") for (int r = 0; r < 4; r++) {                                \
      int o = r * 256 + (TID);                                                     \
      int bb = o >> 6, cc = o & 63;                                                \
      float v = COMB[0][cc*17+bb] + COMB[1][cc*17+bb] + COMB[2][cc*17+bb] + COMB[3][cc*17+bb]; \
      atomicAdd(&(OPTR)[(size_t)bb * (NSTRIDE) + (JBASE) + cc], v);                \
    }                                                                              \
  }

// ---------------- generic gemm (k_per_block=256, j_tile=64): O(16,N) += T(16,K) @ W(K,N) ----------------
__global__ void gemm256_kernel(const float* __restrict__ T,
                               const float* __restrict__ W,
                               float* __restrict__ O,
                               int K, int N) {
  __shared__ __align__(16) float tl[256][20];
  __shared__ float comb[4][64 * 17];
  int tid = threadIdx.x;
  int c = tid & 63, p = tid >> 6;
  int jbase = blockIdx.x * 64;
  int k0 = blockIdx.y * 256;
#pragma unroll
  for (int r = 0; r < 16; r++) {
    int ii = tid + r * 256;
    int b = ii >> 8, k = ii & 255;
    tl[k][b] = T[(size_t)b * K + k0 + k];
  }
  __syncthreads();
  GEMM256_TAIL(tl, comb, W + (size_t)(k0 + p * 64) * N + jbase + c, N, O, jbase, c, p, tid)
}

// ---------------- fused Q+KV gemm (k=256): blocks x<32 -> q, x>=32 -> kv ----------------
__global__ void qkv_gemm_kernel(const float* __restrict__ T,
                                const float* __restrict__ Wq,
                                const float* __restrict__ Wkv,
                                float* __restrict__ Qo,
                                float* __restrict__ KVo) {
  __shared__ __align__(16) float tl[256][20];
  __shared__ float comb[4][64 * 17];
  int tid = threadIdx.x;
  int c = tid & 63, p = tid >> 6;
  int k0 = blockIdx.y * 256;
#pragma unroll
  for (int r = 0; r < 16; r++) {
    int ii = tid + r * 256;
    int b = ii >> 8, k = ii & 255;
    tl[k][b] = T[(size_t)b * D + k0 + k];
  }
  __syncthreads();
  if (blockIdx.x < 32) {
    int jbase = blockIdx.x * 64;
    GEMM256_TAIL(tl, comb, Wq + (size_t)(k0 + p * 64) * D + jbase + c, D, Qo, jbase, c, p, tid)
  } else {
    int jbase = (blockIdx.x - 32) * 64;
    GEMM256_TAIL(tl, comb, Wkv + (size_t)(k0 + p * 64) * 256 + jbase + c, 256, KVo, jbase, c, p, tid)
  }
}

// ---------------- attention split (flash-decoding): block per (b,h,split) ----------------
__global__ void attn_split_kernel(const float* __restrict__ Q,    // (16, 2048)
                                  const float* __restrict__ KVn,  // (16, 256)
                                  const float* __restrict__ KC,
                                  const float* __restrict__ VC,
                                  const int* __restrict__ BT,     // (16, 64)
                                  const int* __restrict__ CL,
                                  float* __restrict__ Pout,       // (256, 8, 128)
                                  float* __restrict__ Pms) {      // (256, 8, 2)
  int bh = blockIdx.x, sp = blockIdx.y;
  int b = bh >> 4, h = bh & 15;
  int ctx = CL[b];
  int s0 = sp * CHUNK;
  if (s0 >= ctx) return;
  int s1 = min(s0 + CHUNK, ctx);
  int n = s1 - s0;
  int last = ctx - 1;
  int tid = threadIdx.x, wid = tid >> 6, lane = tid & 63;
  int half = lane >> 5, l32 = lane & 31;
  __shared__ float sc[CHUNK];
  __shared__ int btl[8];
  __shared__ float4 red[4][64];
  __shared__ float stat[8];
  if (tid < 8) btl[tid] = BT[b * NBLK + sp * 8 + tid];
  __syncthreads();
  float slope = exp2f(-0.5f * (float)(h + 1));
  const float scl = 0.08838834764831845f;   // 1/sqrt(128)
  float4 q4 = ((const float4*)(Q + (size_t)b * D + h * HD))[l32];

  // phase 1: scores — half-wave per position
  for (int base = s0 + wid * 2; base < s1; base += 8) {
    int ps = base + half;
    if (ps < s1) {
      const float* kp = (ps == last) ? KVn + b * 256
                      : KC + ((size_t)btl[(ps - s0) >> 4] * BS_ + (ps & 15)) * (H_ * HD) + h * HD;
      float4 k4 = ((const float4*)kp)[l32];
      float p = q4.x * k4.x + q4.y * k4.y + q4.z * k4.z + q4.w * k4.w;
#pragma unroll
      for (int m = 16; m; m >>= 1) p += __shfl_xor(p, m);
      if (l32 == 0) sc[ps - s0] = p * scl + slope * (float)(ps - last);
    }
  }
  __syncthreads();

  // phase 2: local softmax stats (unnormalized)
  float mx = -1e30f;
  for (int i = tid; i < n; i += 256) mx = fmaxf(mx, sc[i]);
#pragma unroll
  for (int m = 32; m; m >>= 1) mx = fmaxf(mx, __shfl_xor(mx, m));
  if (lane == 0) stat[wid] = mx;
  __syncthreads();
  mx = fmaxf(fmaxf(stat[0], stat[1]), fmaxf(stat[2], stat[3]));
  float sum = 0.f;
  for (int i = tid; i < n; i += 256) { float e = expf(sc[i] - mx); sc[i] = e; sum += e; }
#pragma unroll
  for (int m = 32; m; m >>= 1) sum += __shfl_xor(sum, m);
  if (lane == 0) stat[4 + wid] = sum;
  __syncthreads();

  // phase 3: PV partial (unnormalized) — half-wave per position, float4
  float4 a4 = make_float4(0.f, 0.f, 0.f, 0.f);
  for (int base = s0 + wid * 2; base < s1; base += 8) {
    int ps = base + half;
    if (ps < s1) {
      const float* vp = (ps == last) ? KVn + b * 256 + HD
                      : VC + ((size_t)btl[(ps - s0) >> 4] * BS_ + (ps & 15)) * (H_ * HD) + h * HD;
      float4 v4 = ((const float4*)vp)[l32];
      float p = sc[ps - s0];
      a4.x += p * v4.x; a4.y += p * v4.y; a4.z += p * v4.z; a4.w += p * v4.w;
    }
  }
  red[wid][lane] = a4;
  __syncthreads();
  if (tid < 32) {
    float4 o = make_float4(0.f, 0.f, 0.f, 0.f);
#pragma unroll
    for (int w = 0; w < 4; w++) {
      float4 r0 = red[w][tid], r1 = red[w][tid + 32];
      o.x += r0.x + r1.x; o.y += r0.y + r1.y;
      o.z += r0.z + r1.z; o.w += r0.w + r1.w;
    }
    ((float4*)(Pout + ((size_t)(bh * SPLITS + sp) << 7)))[tid] = o;
  }
  if (tid == 0) {
    Pms[(bh * SPLITS + sp) * 2 + 0] = mx;
    Pms[(bh * SPLITS + sp) * 2 + 1] = stat[4] + stat[5] + stat[6] + stat[7];
  }
}

// ---------------- Wo gemm (k=256) with fused attention-combine staging ----------------
__global__ void wo_gemm_kernel(const float* __restrict__ Pout,
                               const float* __restrict__ Pms,
                               const int* __restrict__ CL,
                               const float* __restrict__ W,
                               float* __restrict__ X) {
  __shared__ __align__(16) float tl[256][20];
  __shared__ float comb[4][64 * 17];
  __shared__ float wgt[16][2][8];
  __shared__ int nspl[16];
  int tid = threadIdx.x;
  int c = tid & 63, p = tid >> 6;
  int jbase = blockIdx.x * 64;
  int k0 = blockIdx.y * 256;
  int h0 = k0 >> 7;
  if (tid < 32) {
    int b = tid & 15, hh = tid >> 4;
    int h = h0 + hh;
    int ctx = CL[b];
    int nsp = (ctx + CHUNK - 1) >> 7;
    if (hh == 0) nspl[b] = nsp;
    int bh = b * 16 + h;
    float M = -1e30f;
#pragma unroll
    for (int i = 0; i < 8; i++) {
      float mi = (i < nsp) ? Pms[(bh * SPLITS + i) * 2] : -1e30f;
      M = fmaxf(M, mi);
    }
    float tot = 0.f, e[8];
#pragma unroll
    for (int i = 0; i < 8; i++) {
      float mi = (i < nsp) ? Pms[(bh * SPLITS + i) * 2] : -1e30f;
      float si = (i < nsp) ? Pms[(bh * SPLITS + i) * 2 + 1] : 0.f;
      e[i] = (i < nsp) ? expf(mi - M) : 0.f;
      tot += e[i] * si;
    }
    float inv = 1.f / tot;
#pragma unroll
    for (int i = 0; i < 8; i++) wgt[b][hh][i] = e[i] * inv;
  }
  __syncthreads();
#pragma unroll
  for (int r = 0; r < 16; r++) {
    int ii = tid + r * 256;
    int b = ii >> 8, k = ii & 255;
    int hh = k >> 7, dd = k & 127;
    int bh = b * 16 + h0 + hh;
    int ns = nspl[b];
    float v = 0.f;
    for (int i = 0; i < ns; i++)
      v += wgt[b][hh][i] * Pout[((size_t)(bh * SPLITS + i) << 7) + dd];
    tl[k][b] = v;
  }
  __syncthreads();
  GEMM256_TAIL(tl, comb, W + (size_t)(k0 + p * 64) * D + jbase + c, D, X, jbase, c, p, tid)
}

// ---------------- Wff2 gemm (k=256) with fused swiglu staging ----------------
__global__ void ff2_gemm_kernel(const float* __restrict__ Hb,
                                const float* __restrict__ W,
                                float* __restrict__ X) {
  __shared__ __align__(16) float tl[256][20];
  __shared__ float comb[4][64 * 17];
  int tid = threadIdx.x;
  int c = tid & 63, p = tid >> 6;
  int jbase = blockIdx.x * 64;
  int k0 = blockIdx.y * 256;
#pragma unroll
  for (int r = 0; r < 16; r++) {
    int ii = tid + r * 256;
    int b = ii >> 8, k = ii & 255;
    float a = Hb[(size_t)b * FF + k0 + k];
    float g = Hb[(size_t)b * FF + 4096 + k0 + k];
    tl[k][b] = a * (g / (1.f + expf(-g)));
  }
  __syncthreads();
  GEMM256_TAIL(tl, comb, W + (size_t)(k0 + p * 64) * D + jbase + c, D, X, jbase, c, p, tid)
}

// ---------------- logits: out(16,V) = T(16,2048) @ wte(V,2048)^T ----------------
// R10-PROVEN FINAL FORM — DO NOT MODIFY IN ANY WAY. 16 rows/block, acc[64],
// pure-global f32 loads, launch_bounds(256,2), unroll 2, butterfly reduce.
// Spill lore: (a) VGPR cap <=128 -> 64-tier + 600-770MB scratch writes (R4/R6/R8);
// (b) acc[32]/8-rows: 1.8x VMEM per wte byte, +36us (R9);
// (c) LDS-staged T across barriers -> 128-tier spill, +160us (R11);
// (d) bf16 T loads (ushort4 unpack) -> 128-tier spill, +160us (R13).
__global__ __launch_bounds__(256, 2)
void logits_kernel(const float* __restrict__ T,
                   const float* __restrict__ wte,
                   float* __restrict__ O) {
  int tid = threadIdx.x;
  int wid = tid >> 6, lane = tid & 63;
  int vbase = blockIdx.x * 16 + wid * 4;
  const float4* T4 = (const float4*)T;            // 16 rows x 512 float4
  const float4* W4 = (const float4*)(wte + (size_t)vbase * D);
  float acc[64];                                   // flat index = b*4 + vi
#pragma unroll
  for (int j = 0; j < 64; j++) acc[j] = 0.f;

#pragma unroll 2
  for (int it = 0; it < 8; it++) {
    int idx = it * 64 + lane;                      // float4 index within row
    float4 w0 = W4[idx];
    float4 w1 = W4[512 + idx];
    float4 w2 = W4[1024 + idx];
    float4 w3 = W4[1536 + idx];
#pragma unroll
    for (int b = 0; b < 16; b++) {
      float4 t4 = T4[b * 512 + idx];
      acc[b * 4 + 0] += t4.x * w0.x + t4.y * w0.y + t4.z * w0.z + t4.w * w0.w;
      acc[b * 4 + 1] += t4.x * w1.x + t4.y * w1.y + t4.z * w1.z + t4.w * w1.w;
      acc[b * 4 + 2] += t4.x * w2.x + t4.y * w2.y + t4.z * w2.z + t4.w * w2.w;
      acc[b * 4 + 3] += t4.x * w3.x + t4.y * w3.y + t4.z * w3.z + t4.w * w3.w;
    }
  }

  // multi-value butterfly reduce: 64 lane-sums in 63 shfls; lane l ends with flat index l.
#pragma unroll
  for (int st = 0; st < 6; st++) {
    const int m = 1 << st;
    const int nn = 64 >> (st + 1);
    const bool hi = (lane & m) != 0;
#pragma unroll
    for (int i = 0; i < nn; i++) {
      float a = acc[2 * i], b = acc[2 * i + 1];
      float send = hi ? a : b;
      float keep = hi ? b : a;
      acc[i] = keep + __shfl_xor(send, m);
    }
  }
  O[(size_t)(lane >> 2) * V_ + vbase + (lane & 3)] = acc[0];
}

extern "C" void kernel_launch(void* const* d_in, const int* in_sizes, int n_in,
                              void* d_out, int out_size, void* d_ws, size_t ws_size,
                              hipStream_t stream) {
  const int* ids   = (const int*)d_in[0];
  const int* bt    = (const int*)d_in[2];
  const int* cl    = (const int*)d_in[3];
  const float* wte = (const float*)d_in[5];
  const float* Wq  = (const float*)d_in[6];
  const float* Wkv = (const float*)d_in[7];
  const float* Wo  = (const float*)d_in[8];
  const float* Wff1= (const float*)d_in[9];
  const float* Wff2= (const float*)d_in[10];
  const float* KC  = (const float*)d_in[11];
  const float* VC  = (const float*)d_in[12];
  float* out = (float*)d_out;
  float* ws  = (float*)d_ws;

  // workspace layout (floats)
  float* x    = ws;             // 16*2048
  float* t    = ws + 32768;     // 16*2048
  float* q    = ws + 65536;     // 16*2048
  float* kv   = ws + 98304;     // 16*256   (contiguous after q -> zeroed together)
  float* hb   = ws + 135168;    // 16*8192
  float* pout = ws + 331776;    // 256*8*128
  float* pms  = ws + 593920;    // 256*8*2

  for (int l = 0; l < L_; l++) {
    // t = ln(x) (layer 0: x = wte[ids] gathered inline); surplus blocks zero q+kv
    ln_kernel<<<16 + 64, 256, 0, stream>>>(x, l == 0 ? ids : nullptr, wte, x, t, q, 32768 + 4096);
    qkv_gemm_kernel<<<dim3(36, 8), 256, 0, stream>>>(t, Wq + (size_t)l * 4194304,
                                                     Wkv + (size_t)l * 524288, q, kv);
    attn_split_kernel<<<dim3(256, SPLITS), 256, 0, stream>>>(q, kv,
                                         KC + (size_t)l * 33554432,
                                         VC + (size_t)l * 33554432,
                                         bt, cl, pout, pms);
    wo_gemm_kernel<<<dim3(32, 8), 256, 0, stream>>>(pout, pms, cl, Wo + (size_t)l * 4194304, x);
    // t = ln(x); surplus blocks zero hb
    ln_kernel<<<16 + 128, 256, 0, stream>>>(x, nullptr, wte, x, t, hb, 131072);
    gemm256_kernel<<<dim3(128, 8), 256, 0, stream>>>(t, Wff1 + (size_t)l * 16777216, hb, 2048, 8192);
    ff2_gemm_kernel<<<dim3(32, 16), 256, 0, stream>>>(hb, Wff2 + (size_t)l * 8388608, x);
  }
  ln_kernel<<<16, 256, 0, stream>>>(x, nullptr, wte, x, t, (float*)nullptr, 0);
  logits_kernel<<<2000, 256, 0, stream>>>(t, wte, out);
}